// Round 19
// baseline (57.326 us; speedup 1.0000x reference)
//
#include <hip/hip_runtime.h>
#include <hip/hip_bf16.h>

#define B_ 16
#define S_ 512
#define D_ 768
#define E_ 16
#define K_ 4

typedef __attribute__((ext_vector_type(8))) short short8;
typedef __attribute__((ext_vector_type(4))) float f32x4;
typedef __attribute__((ext_vector_type(4))) unsigned short u16x4;

#define GLOAD16(gp, lp)                                             \
    __builtin_amdgcn_global_load_lds(                               \
        (const __attribute__((address_space(1))) void*)(gp),        \
        (__attribute__((address_space(3))) void*)(lp), 16, 0, 0)

__device__ __forceinline__ u16x4 pack_bf16x4(f32x4 v) {
    u16x4 pk;
    #pragma unroll
    for (int i = 0; i < 4; ++i) {
        __hip_bfloat16 h = __float2bfloat16(v[i]);
        pk[i] = *(unsigned short*)&h;
    }
    return pk;
}

// ---- K1: DIAGNOSTIC double-run (x pointer laundered per rep; stores idempotent) -------
__global__ void k1_mean_cvt(const float* __restrict__ x, __hip_bfloat16* __restrict__ xb,
                            float* __restrict__ partial) {
    int t  = threadIdx.x;          // 0..191
    int b  = blockIdx.x;           // 0..15
    int sc = blockIdx.y;           // 0..15 (s chunk of 32)
    size_t rowbase = ((size_t)b * S_ + (size_t)sc * 32) * D_ + t * 4;

    for (int rep = 0; rep < 2; ++rep) {
        unsigned long long xp64 = (unsigned long long)x;
        asm volatile("" : "+s"(xp64));          // opaque: forces re-load on rep 1
        const float* xr = (const float*)xp64;

        float4 acc = make_float4(0.f, 0.f, 0.f, 0.f);
        #pragma unroll 8
        for (int s = 0; s < 32; ++s) {
            float4 v = *(const float4*)(xr + rowbase + (size_t)s * D_);
            acc.x += v.x; acc.y += v.y; acc.z += v.z; acc.w += v.w;
            __hip_bfloat16 h0 = __float2bfloat16(v.x);
            __hip_bfloat16 h1 = __float2bfloat16(v.y);
            __hip_bfloat16 h2 = __float2bfloat16(v.z);
            __hip_bfloat16 h3 = __float2bfloat16(v.w);
            ushort4 pk;
            pk.x = *(unsigned short*)&h0; pk.y = *(unsigned short*)&h1;
            pk.z = *(unsigned short*)&h2; pk.w = *(unsigned short*)&h3;
            *(ushort4*)((unsigned short*)xb + rowbase + (size_t)s * D_) = pk;
        }
        *(float4*)(partial + ((size_t)sc * B_ + b) * D_ + t * 4) = acc;
    }
}

// ---- K2a: DIAGNOSTIC double-run (inputs laundered; both reps bit-identical) -----------
__global__ void k2a_logits(const float* __restrict__ partial,
                           const float* __restrict__ noise,
                           const float* __restrict__ w_gate,
                           const float* __restrict__ w_noise,
                           const float* __restrict__ thr_ptr,
                           float* __restrict__ gates_out,
                           float* __restrict__ clean_out,
                           float* __restrict__ std_out,
                           float* __restrict__ noisy_out,
                           float* __restrict__ thrin_out,
                           float* __restrict__ throut_out) {
    __shared__ float xm[D_];
    __shared__ float red[2][16][17];
    __shared__ float s_noisy[E_];

    int b = blockIdx.x, t = threadIdx.x;

    for (int rep = 0; rep < 2; ++rep) {
        unsigned long long pp64 = (unsigned long long)partial;
        unsigned long long wg64 = (unsigned long long)w_gate;
        unsigned long long wn64 = (unsigned long long)w_noise;
        asm volatile("" : "+s"(pp64), "+s"(wg64), "+s"(wn64));
        const float* par = (const float*)pp64;
        const float* wgp = (const float*)wg64;
        const float* wnp = (const float*)wn64;

        __syncthreads();   // WAR guard on shared arrays between reps

        for (int d = t; d < D_; d += 256) {
            float s = 0.f;
            #pragma unroll
            for (int c = 0; c < 16; ++c) s += par[((size_t)c * B_ + b) * D_ + d];
            xm[d] = s * (1.0f / S_);
        }
        __syncthreads();

        int e = t & 15, sl = t >> 4;
        const float* wg = wgp + (size_t)sl * 48 * E_ + e;
        const float* wn = wnp + (size_t)sl * 48 * E_ + e;
        float cl = 0.f, nz = 0.f;
        #pragma unroll
        for (int i = 0; i < 48; ++i) {
            float xv = xm[sl * 48 + i];
            cl += xv * wg[(size_t)i * E_];
            nz += xv * wn[(size_t)i * E_];
        }
        red[0][sl][e] = cl;
        red[1][sl][e] = nz;
        __syncthreads();

        if (t < E_) {
            float c2 = 0.f, n2 = 0.f;
            #pragma unroll
            for (int s2 = 0; s2 < 16; ++s2) { c2 += red[0][s2][t]; n2 += red[1][s2][t]; }
            float sp     = fmaxf(n2, 0.f) + log1pf(expf(-fabsf(n2)));
            float stddev = sp + 0.01f;
            float ny     = c2 + noise[b * E_ + t] * stddev;
            s_noisy[t] = ny;
            clean_out[b * E_ + t] = c2;
            std_out[b * E_ + t]   = stddev;
            noisy_out[b * E_ + t] = ny;
        }
        __syncthreads();

        if (t < E_) {
            float ny = s_noisy[t];
            int rank = 0;
            #pragma unroll
            for (int j = 0; j < E_; ++j) {
                float vj = s_noisy[j];
                if (vj > ny || (vj == ny && j < t)) rank++;
            }
            if (rank == K_)     thrin_out[b]  = ny;
            if (rank == K_ - 1) throut_out[b] = ny;

            float mx = -1e30f;
            #pragma unroll
            for (int j = 0; j < E_; ++j) mx = fmaxf(mx, s_noisy[j]);
            float den = 0.f;
            #pragma unroll
            for (int j = 0; j < E_; ++j) den += expf(s_noisy[j] - mx);
            float gate = expf(ny - mx) / den;
            float sig  = 1.f / (1.f + expf(-thr_ptr[0]));
            gates_out[b * E_ + t] = fmaxf(gate - sig, 0.f);
        }
    }
}

// ------- K3: Wb mix, MLP-restructured (R17 best; byte-identical) -----------------------
__global__ __launch_bounds__(256) void k3_wb(
        const float* __restrict__ gates, const float* __restrict__ weight,
        const float* __restrict__ bias,
        const float* __restrict__ clean,
        const float* __restrict__ stdv,
        const float* __restrict__ noisyv,
        const float* __restrict__ thrin,
        const float* __restrict__ throut,
        __hip_bfloat16* __restrict__ wb, float* __restrict__ ebias,
        float* __restrict__ loss_out) {
    __shared__ float g[B_ * E_];
    int t = threadIdx.x;
    g[t] = gates[t];
    __syncthreads();

    int blk = blockIdx.x;

    if (blk == 2352) {                       // loss block
        __shared__ float s_imp[E_], s_load[E_];
        if (t < E_) {
            float imp = 0.f, ld = 0.f;
            #pragma unroll
            for (int bb = 0; bb < B_; ++bb) {
                imp += g[bb * E_ + t];
                float ti = thrin[bb], to = throut[bb];
                float c2 = clean[bb * E_ + t], sd = stdv[bb * E_ + t], nl = noisyv[bb * E_ + t];
                float z  = (nl > ti) ? (c2 - ti) / sd : (c2 - to) / sd;
                ld += 0.5f * erfcf(-z * 0.70710678118654752f);   // Phi(z)
            }
            s_imp[t]  = imp;
            s_load[t] = ld;
        }
        __syncthreads();
        if (t == 0) {
            float m1 = 0.f, m2 = 0.f;
            #pragma unroll
            for (int j = 0; j < E_; ++j) { m1 += s_imp[j]; m2 += s_load[j]; }
            m1 /= E_; m2 /= E_;
            float v1 = 0.f, v2 = 0.f;
            #pragma unroll
            for (int j = 0; j < E_; ++j) {
                float a = s_imp[j]  - m1; v1 += a * a;
                float c = s_load[j] - m2; v2 += c * c;
            }
            v1 /= (E_ - 1); v2 /= (E_ - 1);                      // ddof=1
            loss_out[0] = (v1 / (m1 * m1 + 1e-10f) + v2 / (m2 * m2 + 1e-10f)) * 0.01f;
        }
        return;
    }

    if (blk >= 2304) {                       // bias-mix tail blocks
        int idx = (blk - 2304) * 256 + t;    // 0..12287 = B_*D_
        int b = idx / D_, o = idx % D_;
        float acc = 0.f;
        #pragma unroll
        for (int e = 0; e < E_; ++e) acc += g[b * E_ + e] * bias[e * D_ + o];
        ebias[idx] = acc;
        return;
    }

    int gran = blk * 64 + (t & 63);          // float4-granule of D*D
    int q    = t >> 6;                        // wave id = b-quad
    size_t base = (size_t)gran * 4;

    f32x4 acc0 = {0.f,0.f,0.f,0.f}, acc1 = {0.f,0.f,0.f,0.f};
    f32x4 acc2 = {0.f,0.f,0.f,0.f}, acc3 = {0.f,0.f,0.f,0.f};
    #pragma unroll
    for (int e = 0; e < E_; ++e) {
        f32x4 w4 = *(const f32x4*)(weight + (size_t)e * D_ * D_ + base);
        acc0 += g[(q * 4 + 0) * E_ + e] * w4;
        acc1 += g[(q * 4 + 1) * E_ + e] * w4;
        acc2 += g[(q * 4 + 2) * E_ + e] * w4;
        acc3 += g[(q * 4 + 3) * E_ + e] * w4;
    }
    unsigned short* wbp = (unsigned short*)wb;
    *(u16x4*)(wbp + (size_t)(q * 4 + 0) * D_ * D_ + base) = pack_bf16x4(acc0);
    *(u16x4*)(wbp + (size_t)(q * 4 + 1) * D_ * D_ + base) = pack_bf16x4(acc1);
    *(u16x4*)(wbp + (size_t)(q * 4 + 2) * D_ * D_ + base) = pack_bf16x4(acc2);
    *(u16x4*)(wbp + (size_t)(q * 4 + 3) * D_ * D_ + base) = pack_bf16x4(acc3);
}

// -- K4: batched GEMM (R9/R17 structure; byte-identical) --------------------------------
#define BM 128
#define BN 96
#define BK 64
#define NT (D_ / BK)   // 12 K-tiles

__global__ __launch_bounds__(256, 2) void k4_gemm(const __hip_bfloat16* __restrict__ xb,
                                                  const __hip_bfloat16* __restrict__ wbm,
                                                  const float* __restrict__ ebias,
                                                  float* __restrict__ y) {
    __shared__ __hip_bfloat16 As[2][BM][BK];   // 32 KB
    __shared__ __hip_bfloat16 Bs[2][BN][BK];   // 24 KB

    int t = threadIdx.x;
    int wgid  = blockIdx.x;        // 0..511
    int xcd   = wgid & 7;
    int local = wgid >> 3;         // 0..63
    int b  = (xcd << 1) | (local & 1);
    int r2 = local >> 1;           // 0..31
    int bm = r2 & 3;               // 0..3  (512/128)
    int bn = r2 >> 2;              // 0..7  (768/96)

    const __hip_bfloat16* xp = xb  + (size_t)b * S_ * D_ + (size_t)(bm * BM) * D_;
    const __hip_bfloat16* wp = wbm + (size_t)b * D_ * D_ + (size_t)(bn * BN) * D_;

    int wave = t >> 6, lane = t & 63;
    int wm = wave >> 1, wn = wave & 1;         // 2x2 waves, each 64x48 out
    int lrow = lane & 15;
    int lk   = (lane >> 4) << 3;               // 0,8,16,24
    int swz  = (lrow & 7) << 3;                // read-side XOR (elem units)

    int lr  = lane >> 3;                       // 0..7
    int lcs = (((lane & 7) ^ lr) << 3);        // pre-swizzled source col (rule #21)

    f32x4 zero4 = {0.f, 0.f, 0.f, 0.f};
    f32x4 acc[4][3];
    #pragma unroll
    for (int m = 0; m < 4; ++m)
        #pragma unroll
        for (int n = 0; n < 3; ++n) acc[m][n] = zero4;

    #define STAGE(buf, k0)                                                          \
        do {                                                                        \
            _Pragma("unroll")                                                       \
            for (int i = 0; i < 4; ++i) {                                           \
                int r = wave * 32 + i * 8;                                          \
                GLOAD16(xp + (size_t)(r + lr) * D_ + (k0) + lcs, &As[buf][r][0]);   \
            }                                                                       \
            _Pragma("unroll")                                                       \
            for (int i = 0; i < 3; ++i) {                                           \
                int r = wave * 24 + i * 8;                                          \
                GLOAD16(wp + (size_t)(r + lr) * D_ + (k0) + lcs, &Bs[buf][r][0]);   \
            }                                                                       \
        } while (0)

    #define COMPUTE(buf)                                                            \
        do {                                                                        \
            _Pragma("unroll")                                                       \
            for (int kk = 0; kk < BK; kk += 32) {                                   \
                short8 afr[4], bfr[3];                                              \
                _Pragma("unroll")                                                   \
                for (int m = 0; m < 4; ++m)                                         \
                    afr[m] = *(const short8*)(&As[buf][wm * 64 + m * 16 + lrow]     \
                                                 [(kk + lk) ^ swz]);                \
                _Pragma("unroll")                                                   \
                for (int n = 0; n < 3; ++n)                                         \
                    bfr[n] = *(const short8*)(&Bs[buf][wn * 48 + n * 16 + lrow]     \
                                                 [(kk + lk) ^ swz]);                \
                _Pragma("unroll")                                                   \
                for (int m = 0; m < 4; ++m)                                         \
                    _Pragma("unroll")                                               \
                    for (int n = 0; n < 3; ++n)                                     \
                        acc[m][n] = __builtin_amdgcn_mfma_f32_16x16x32_bf16(        \
                            afr[m], bfr[n], acc[m][n], 0, 0, 0);                    \
            }                                                                       \
        } while (0)

    STAGE(0, 0);
    __syncthreads();
    int cur = 0;
    for (int kt = 0; kt < NT - 1; ++kt) {
        STAGE(cur ^ 1, (kt + 1) * BK);
        COMPUTE(cur);
        __syncthreads();
        cur ^= 1;
    }
    COMPUTE(cur);

    float* yp = y + (size_t)b * S_ * D_ + (size_t)(bm * BM) * D_ + bn * BN;
    const float* ep = ebias + (size_t)b * D_ + bn * BN;
    int crow = (lane >> 4) * 4;
    int ccol = lane & 15;
    #pragma unroll
    for (int n = 0; n < 3; ++n) {
        float eb = ep[wn * 48 + n * 16 + ccol];
        #pragma unroll
        for (int m = 0; m < 4; ++m) {
            #pragma unroll
            for (int j = 0; j < 4; ++j) {
                __builtin_nontemporal_store(acc[m][n][j] + eb,
                    yp + (size_t)(wm * 64 + m * 16 + crow + j) * D_ + wn * 48 + n * 16 + ccol);
            }
        }
    }
    #undef STAGE
    #undef COMPUTE
}

// -------------------------------------------------------------------------------------
extern "C" void kernel_launch(void* const* d_in, const int* in_sizes, int n_in,
                              void* d_out, int out_size, void* d_ws, size_t ws_size,
                              hipStream_t stream) {
    const float* x       = (const float*)d_in[0];
    const float* noise   = (const float*)d_in[1];
    const float* w_gate  = (const float*)d_in[2];
    const float* w_noise = (const float*)d_in[3];
    const float* thr     = (const float*)d_in[4];
    const float* weight  = (const float*)d_in[5];
    const float* bias    = (const float*)d_in[6];
    float* out = (float*)d_out;   // y [B*S*D] then loss [1]

    char* ws = (char*)d_ws;
    float*          partial = (float*)(ws + 0);               // 16*B*D f32 = 786432 B
    float*          gates   = (float*)(ws + 786432);
    float*          clean   = (float*)(ws + 787456);
    float*          stdv    = (float*)(ws + 788480);
    float*          noisyv  = (float*)(ws + 789504);
    float*          thrin   = (float*)(ws + 790528);
    float*          throut  = (float*)(ws + 790592);
    float*          ebias   = (float*)(ws + 790656);          // B*D f32
    __hip_bfloat16* xb      = (__hip_bfloat16*)(ws + 839808);     // B*S*D bf16
    __hip_bfloat16* wb      = (__hip_bfloat16*)(ws + 13422720);   // B*D*D bf16

    k1_mean_cvt<<<dim3(B_, 16), 192, 0, stream>>>(x, xb, partial);
    k2a_logits<<<16, 256, 0, stream>>>(partial, noise, w_gate, w_noise, thr, gates,
                                       clean, stdv, noisyv, thrin, throut);
    k3_wb<<<2353, 256, 0, stream>>>(gates, weight, bias, clean, stdv, noisyv, thrin, throut,
                                    wb, ebias, out + (size_t)B_ * S_ * D_);
    k4_gemm<<<512, 256, 0, stream>>>(xb, wb, ebias, out);
}

// Round 20
// 50.185 us; speedup vs baseline: 1.1423x; 1.1423x over previous
//
#include <hip/hip_runtime.h>
#include <hip/hip_bf16.h>

#define B_ 16
#define S_ 512
#define D_ 768
#define E_ 16
#define K_ 4

typedef __attribute__((ext_vector_type(8))) short short8;
typedef __attribute__((ext_vector_type(4))) float f32x4;
typedef __attribute__((ext_vector_type(4))) unsigned short u16x4;
typedef __attribute__((ext_vector_type(8))) unsigned short u16x8;

#define GLOAD16(gp, lp)                                             \
    __builtin_amdgcn_global_load_lds(                               \
        (const __attribute__((address_space(1))) void*)(gp),        \
        (__attribute__((address_space(3))) void*)(lp), 16, 0, 0)

__device__ __forceinline__ u16x8 pack_bf16x8(f32x4 a, f32x4 b) {
    u16x8 pk;
    #pragma unroll
    for (int i = 0; i < 4; ++i) {
        __hip_bfloat16 h = __float2bfloat16(a[i]);
        pk[i] = *(unsigned short*)&h;
    }
    #pragma unroll
    for (int i = 0; i < 4; ++i) {
        __hip_bfloat16 h = __float2bfloat16(b[i]);
        pk[4 + i] = *(unsigned short*)&h;
    }
    return pk;
}

// ---------------- K1: column means (16 s-chunks) + x -> bf16, vectorized ---------------
__global__ void k1_mean_cvt(const float* __restrict__ x, __hip_bfloat16* __restrict__ xb,
                            float* __restrict__ partial) {
    int t  = threadIdx.x;          // 0..191
    int b  = blockIdx.x;           // 0..15
    int sc = blockIdx.y;           // 0..15 (s chunk of 32)
    size_t rowbase = ((size_t)b * S_ + (size_t)sc * 32) * D_ + t * 4;

    float4 acc = make_float4(0.f, 0.f, 0.f, 0.f);
    #pragma unroll 8
    for (int s = 0; s < 32; ++s) {
        float4 v = *(const float4*)(x + rowbase + (size_t)s * D_);
        acc.x += v.x; acc.y += v.y; acc.z += v.z; acc.w += v.w;
        __hip_bfloat16 h0 = __float2bfloat16(v.x);
        __hip_bfloat16 h1 = __float2bfloat16(v.y);
        __hip_bfloat16 h2 = __float2bfloat16(v.z);
        __hip_bfloat16 h3 = __float2bfloat16(v.w);
        ushort4 pk;
        pk.x = *(unsigned short*)&h0; pk.y = *(unsigned short*)&h1;
        pk.z = *(unsigned short*)&h2; pk.w = *(unsigned short*)&h3;
        *(ushort4*)((unsigned short*)xb + rowbase + (size_t)s * D_) = pk;
    }
    *(float4*)(partial + ((size_t)sc * B_ + b) * D_ + t * 4) = acc;
}

// ---------------- K2a: per-batch gating (16 blocks, d-parallel dot products) -----------
__global__ void k2a_logits(const float* __restrict__ partial,
                           const float* __restrict__ noise,
                           const float* __restrict__ w_gate,
                           const float* __restrict__ w_noise,
                           const float* __restrict__ thr_ptr,
                           float* __restrict__ gates_out,
                           float* __restrict__ clean_out,
                           float* __restrict__ std_out,
                           float* __restrict__ noisy_out,
                           float* __restrict__ thrin_out,
                           float* __restrict__ throut_out) {
    __shared__ float xm[D_];
    __shared__ float red[2][16][17];
    __shared__ float s_noisy[E_];

    int b = blockIdx.x, t = threadIdx.x;

    for (int d = t; d < D_; d += 256) {
        float s = 0.f;
        #pragma unroll
        for (int c = 0; c < 16; ++c) s += partial[((size_t)c * B_ + b) * D_ + d];
        xm[d] = s * (1.0f / S_);
    }
    __syncthreads();

    int e = t & 15, sl = t >> 4;
    const float* wg = w_gate  + (size_t)sl * 48 * E_ + e;
    const float* wn = w_noise + (size_t)sl * 48 * E_ + e;
    float cl = 0.f, nz = 0.f;
    #pragma unroll
    for (int i = 0; i < 48; ++i) {
        float xv = xm[sl * 48 + i];
        cl += xv * wg[(size_t)i * E_];
        nz += xv * wn[(size_t)i * E_];
    }
    red[0][sl][e] = cl;
    red[1][sl][e] = nz;
    __syncthreads();

    if (t < E_) {
        float c2 = 0.f, n2 = 0.f;
        #pragma unroll
        for (int s2 = 0; s2 < 16; ++s2) { c2 += red[0][s2][t]; n2 += red[1][s2][t]; }
        float sp     = fmaxf(n2, 0.f) + log1pf(expf(-fabsf(n2)));
        float stddev = sp + 0.01f;
        float ny     = c2 + noise[b * E_ + t] * stddev;
        s_noisy[t] = ny;
        clean_out[b * E_ + t] = c2;
        std_out[b * E_ + t]   = stddev;
        noisy_out[b * E_ + t] = ny;
    }
    __syncthreads();

    if (t < E_) {
        float ny = s_noisy[t];
        int rank = 0;
        #pragma unroll
        for (int j = 0; j < E_; ++j) {
            float vj = s_noisy[j];
            if (vj > ny || (vj == ny && j < t)) rank++;
        }
        if (rank == K_)     thrin_out[b]  = ny;
        if (rank == K_ - 1) throut_out[b] = ny;

        float mx = -1e30f;
        #pragma unroll
        for (int j = 0; j < E_; ++j) mx = fmaxf(mx, s_noisy[j]);
        float den = 0.f;
        #pragma unroll
        for (int j = 0; j < E_; ++j) den += expf(s_noisy[j] - mx);
        float gate = expf(ny - mx) / den;
        float sig  = 1.f / (1.f + expf(-thr_ptr[0]));
        gates_out[b * E_ + t] = fmaxf(gate - sig, 0.f);
    }
}

// ------- K3: Wb mix, 16B-store restructure (thread = 2 granules x b-quad) --------------
// blocks 0..1151: mix (128 granules each); 1152..1199: ebias; 1200: cv^2 loss
__global__ __launch_bounds__(256) void k3_wb(
        const float* __restrict__ gates, const float* __restrict__ weight,
        const float* __restrict__ bias,
        const float* __restrict__ clean,
        const float* __restrict__ stdv,
        const float* __restrict__ noisyv,
        const float* __restrict__ thrin,
        const float* __restrict__ throut,
        __hip_bfloat16* __restrict__ wb, float* __restrict__ ebias,
        float* __restrict__ loss_out) {
    __shared__ float g[B_ * E_];
    int t = threadIdx.x;
    g[t] = gates[t];
    __syncthreads();

    int blk = blockIdx.x;

    if (blk == 1200) {                       // loss block
        __shared__ float s_imp[E_], s_load[E_];
        if (t < E_) {
            float imp = 0.f, ld = 0.f;
            #pragma unroll
            for (int bb = 0; bb < B_; ++bb) {
                imp += g[bb * E_ + t];
                float ti = thrin[bb], to = throut[bb];
                float c2 = clean[bb * E_ + t], sd = stdv[bb * E_ + t], nl = noisyv[bb * E_ + t];
                float z  = (nl > ti) ? (c2 - ti) / sd : (c2 - to) / sd;
                ld += 0.5f * erfcf(-z * 0.70710678118654752f);   // Phi(z)
            }
            s_imp[t]  = imp;
            s_load[t] = ld;
        }
        __syncthreads();
        if (t == 0) {
            float m1 = 0.f, m2 = 0.f;
            #pragma unroll
            for (int j = 0; j < E_; ++j) { m1 += s_imp[j]; m2 += s_load[j]; }
            m1 /= E_; m2 /= E_;
            float v1 = 0.f, v2 = 0.f;
            #pragma unroll
            for (int j = 0; j < E_; ++j) {
                float a = s_imp[j]  - m1; v1 += a * a;
                float c = s_load[j] - m2; v2 += c * c;
            }
            v1 /= (E_ - 1); v2 /= (E_ - 1);                      // ddof=1
            loss_out[0] = (v1 / (m1 * m1 + 1e-10f) + v2 / (m2 * m2 + 1e-10f)) * 0.01f;
        }
        return;
    }

    if (blk >= 1152) {                       // bias-mix tail blocks
        int idx = (blk - 1152) * 256 + t;    // 0..12287 = B_*D_
        int b = idx / D_, o = idx % D_;
        float acc = 0.f;
        #pragma unroll
        for (int e = 0; e < E_; ++e) acc += g[b * E_ + e] * bias[e * D_ + o];
        ebias[idx] = acc;
        return;
    }

    // mix: block covers 512 floats (128 granules); thread = 2 consecutive granules
    // (32B loads per expert) for wave's b-quad; stores are u16x8 = 16B (dwordx4).
    int lane = t & 63, wv = t >> 6;
    size_t fbase = (size_t)blk * 512 + lane * 8;   // float index, 32B-aligned
    int rot = blk & 15;                            // per-block expert rotation

    f32x4 a0g0 = {0,0,0,0}, a0g1 = {0,0,0,0};
    f32x4 a1g0 = {0,0,0,0}, a1g1 = {0,0,0,0};
    f32x4 a2g0 = {0,0,0,0}, a2g1 = {0,0,0,0};
    f32x4 a3g0 = {0,0,0,0}, a3g1 = {0,0,0,0};
    #pragma unroll
    for (int ee = 0; ee < E_; ++ee) {
        int e = (ee + rot) & 15;
        const float* wp = weight + (size_t)e * D_ * D_ + fbase;
        f32x4 w0 = *(const f32x4*)wp;
        f32x4 w1 = *(const f32x4*)(wp + 4);
        float g0 = g[(wv * 4 + 0) * E_ + e];
        float g1 = g[(wv * 4 + 1) * E_ + e];
        float g2 = g[(wv * 4 + 2) * E_ + e];
        float g3 = g[(wv * 4 + 3) * E_ + e];
        a0g0 += g0 * w0; a0g1 += g0 * w1;
        a1g0 += g1 * w0; a1g1 += g1 * w1;
        a2g0 += g2 * w0; a2g1 += g2 * w1;
        a3g0 += g3 * w0; a3g1 += g3 * w1;
    }
    unsigned short* wbp = (unsigned short*)wb;
    *(u16x8*)(wbp + (size_t)(wv * 4 + 0) * D_ * D_ + fbase) = pack_bf16x8(a0g0, a0g1);
    *(u16x8*)(wbp + (size_t)(wv * 4 + 1) * D_ * D_ + fbase) = pack_bf16x8(a1g0, a1g1);
    *(u16x8*)(wbp + (size_t)(wv * 4 + 2) * D_ * D_ + fbase) = pack_bf16x8(a2g0, a2g1);
    *(u16x8*)(wbp + (size_t)(wv * 4 + 3) * D_ * D_ + fbase) = pack_bf16x8(a3g0, a3g1);
}

// -- K4: batched GEMM, 128x96 tile, 512 blocks (2/CU), XCD-local b, T2 swizzle ----------
#define BM 128
#define BN 96
#define BK 64
#define NT (D_ / BK)   // 12 K-tiles

__global__ __launch_bounds__(256, 2) void k4_gemm(const __hip_bfloat16* __restrict__ xb,
                                                  const __hip_bfloat16* __restrict__ wbm,
                                                  const float* __restrict__ ebias,
                                                  float* __restrict__ y) {
    __shared__ __hip_bfloat16 As[2][BM][BK];   // 32 KB
    __shared__ __hip_bfloat16 Bs[2][BN][BK];   // 24 KB

    int t = threadIdx.x;
    int wgid  = blockIdx.x;        // 0..511
    int xcd   = wgid & 7;
    int local = wgid >> 3;         // 0..63
    int b  = (xcd << 1) | (local & 1);
    int r2 = local >> 1;           // 0..31
    int bm = r2 & 3;               // 0..3  (512/128)
    int bn = r2 >> 2;              // 0..7  (768/96)

    const __hip_bfloat16* xp = xb  + (size_t)b * S_ * D_ + (size_t)(bm * BM) * D_;
    const __hip_bfloat16* wp = wbm + (size_t)b * D_ * D_ + (size_t)(bn * BN) * D_;

    int wave = t >> 6, lane = t & 63;
    int wm = wave >> 1, wn = wave & 1;         // 2x2 waves, each 64x48 out
    int lrow = lane & 15;
    int lk   = (lane >> 4) << 3;               // 0,8,16,24
    int swz  = (lrow & 7) << 3;                // read-side XOR (elem units)

    int lr  = lane >> 3;                       // 0..7
    int lcs = (((lane & 7) ^ lr) << 3);        // pre-swizzled source col (rule #21)

    f32x4 zero4 = {0.f, 0.f, 0.f, 0.f};
    f32x4 acc[4][3];
    #pragma unroll
    for (int m = 0; m < 4; ++m)
        #pragma unroll
        for (int n = 0; n < 3; ++n) acc[m][n] = zero4;

    #define STAGE(buf, k0)                                                          \
        do {                                                                        \
            _Pragma("unroll")                                                       \
            for (int i = 0; i < 4; ++i) {                                           \
                int r = wave * 32 + i * 8;                                          \
                GLOAD16(xp + (size_t)(r + lr) * D_ + (k0) + lcs, &As[buf][r][0]);   \
            }                                                                       \
            _Pragma("unroll")                                                       \
            for (int i = 0; i < 3; ++i) {                                           \
                int r = wave * 24 + i * 8;                                          \
                GLOAD16(wp + (size_t)(r + lr) * D_ + (k0) + lcs, &Bs[buf][r][0]);   \
            }                                                                       \
        } while (0)

    #define COMPUTE(buf)                                                            \
        do {                                                                        \
            _Pragma("unroll")                                                       \
            for (int kk = 0; kk < BK; kk += 32) {                                   \
                short8 afr[4], bfr[3];                                              \
                _Pragma("unroll")                                                   \
                for (int m = 0; m < 4; ++m)                                         \
                    afr[m] = *(const short8*)(&As[buf][wm * 64 + m * 16 + lrow]     \
                                                 [(kk + lk) ^ swz]);                \
                _Pragma("unroll")                                                   \
                for (int n = 0; n < 3; ++n)                                         \
                    bfr[n] = *(const short8*)(&Bs[buf][wn * 48 + n * 16 + lrow]     \
                                                 [(kk + lk) ^ swz]);                \
                _Pragma("unroll")                                                   \
                for (int m = 0; m < 4; ++m)                                         \
                    _Pragma("unroll")                                               \
                    for (int n = 0; n < 3; ++n)                                     \
                        acc[m][n] = __builtin_amdgcn_mfma_f32_16x16x32_bf16(        \
                            afr[m], bfr[n], acc[m][n], 0, 0, 0);                    \
            }                                                                       \
        } while (0)

    STAGE(0, 0);
    __syncthreads();
    int cur = 0;
    for (int kt = 0; kt < NT - 1; ++kt) {
        STAGE(cur ^ 1, (kt + 1) * BK);
        COMPUTE(cur);
        __syncthreads();
        cur ^= 1;
    }
    COMPUTE(cur);

    float* yp = y + (size_t)b * S_ * D_ + (size_t)(bm * BM) * D_ + bn * BN;
    const float* ep = ebias + (size_t)b * D_ + bn * BN;
    int crow = (lane >> 4) * 4;
    int ccol = lane & 15;
    #pragma unroll
    for (int n = 0; n < 3; ++n) {
        float eb = ep[wn * 48 + n * 16 + ccol];
        #pragma unroll
        for (int m = 0; m < 4; ++m) {
            #pragma unroll
            for (int j = 0; j < 4; ++j) {
                __builtin_nontemporal_store(acc[m][n][j] + eb,
                    yp + (size_t)(wm * 64 + m * 16 + crow + j) * D_ + wn * 48 + n * 16 + ccol);
            }
        }
    }
    #undef STAGE
    #undef COMPUTE
}

// -------------------------------------------------------------------------------------
extern "C" void kernel_launch(void* const* d_in, const int* in_sizes, int n_in,
                              void* d_out, int out_size, void* d_ws, size_t ws_size,
                              hipStream_t stream) {
    const float* x       = (const float*)d_in[0];
    const float* noise   = (const float*)d_in[1];
    const float* w_gate  = (const float*)d_in[2];
    const float* w_noise = (const float*)d_in[3];
    const float* thr     = (const float*)d_in[4];
    const float* weight  = (const float*)d_in[5];
    const float* bias    = (const float*)d_in[6];
    float* out = (float*)d_out;   // y [B*S*D] then loss [1]

    char* ws = (char*)d_ws;
    float*          partial = (float*)(ws + 0);               // 16*B*D f32 = 786432 B
    float*          gates   = (float*)(ws + 786432);
    float*          clean   = (float*)(ws + 787456);
    float*          stdv    = (float*)(ws + 788480);
    float*          noisyv  = (float*)(ws + 789504);
    float*          thrin   = (float*)(ws + 790528);
    float*          throut  = (float*)(ws + 790592);
    float*          ebias   = (float*)(ws + 790656);          // B*D f32
    __hip_bfloat16* xb      = (__hip_bfloat16*)(ws + 839808);     // B*S*D bf16
    __hip_bfloat16* wb      = (__hip_bfloat16*)(ws + 13422720);   // B*D*D bf16

    k1_mean_cvt<<<dim3(B_, 16), 192, 0, stream>>>(x, xb, partial);
    k2a_logits<<<16, 256, 0, stream>>>(partial, noise, w_gate, w_noise, thr, gates,
                                       clean, stdv, noisyv, thrin, throut);
    k3_wb<<<1201, 256, 0, stream>>>(gates, weight, bias, clean, stdv, noisyv, thrin, throut,
                                    wb, ebias, out + (size_t)B_ * S_ * D_);
    k4_gemm<<<512, 256, 0, stream>>>(xb, wb, ebias, out);
}